// Round 3
// baseline (536.766 us; speedup 1.0000x reference)
//
#include <hip/hip_runtime.h>
#include <hip/hip_bf16.h>
#include <stdint.h>

// NeighborAttention fused kernel, MI355X gfx950 — dtype-robust diagnostic round.
// B=4,N=4096,K=32,C=128,H=4,d=32. Mask int32. Float tensors: dtype detected at
// runtime (fp32 vs bf16) by a 1-block detector kernel writing a flag to d_ws;
// both template variants launch, the wrong one early-returns uniformly.
// One block = 4 nodes, 256 threads (4 waves). Grid = 4096.

typedef __attribute__((ext_vector_type(8))) short short8;   // 8 bf16 = 16 B
typedef __attribute__((ext_vector_type(4))) float f32x4;

#define NPB   4
#define CDIM  128
#define KN    32
#define LSTR  136   // LDS row stride in bf16 units (272 B, multiple of 16 B)

__device__ __forceinline__ float bf2f(short s) {
    union { unsigned int u; float f; } v;
    v.u = ((unsigned int)(unsigned short)s) << 16;
    return v.f;
}
__device__ __forceinline__ short f2bf(float f) {
    union { float ff; unsigned int u; } v; v.ff = f;
    unsigned int u = v.u;
    u += 0x7FFFu + ((u >> 16) & 1u);   // round-to-nearest-even
    return (short)(u >> 16);
}

struct f8 { float v[8]; };

// load 8 consecutive logical elements starting at elem index idx, as bf16
template<bool FP32>
__device__ __forceinline__ short8 load8bf(const void* p, size_t idx) {
    if constexpr (FP32) {
        const float* fp = (const float*)p + idx;
        f32x4 a = *(const f32x4*)fp;
        f32x4 b = *(const f32x4*)(fp + 4);
        short8 r;
        r[0] = f2bf(a[0]); r[1] = f2bf(a[1]); r[2] = f2bf(a[2]); r[3] = f2bf(a[3]);
        r[4] = f2bf(b[0]); r[5] = f2bf(b[1]); r[6] = f2bf(b[2]); r[7] = f2bf(b[3]);
        return r;
    } else {
        return *(const short8*)((const short*)p + idx);
    }
}

// load 8 consecutive logical elements as fp32
template<bool FP32>
__device__ __forceinline__ f8 loadf8(const void* p, size_t idx) {
    f8 r;
    if constexpr (FP32) {
        const float* fp = (const float*)p + idx;
        f32x4 a = *(const f32x4*)fp;
        f32x4 b = *(const f32x4*)(fp + 4);
        r.v[0] = a[0]; r.v[1] = a[1]; r.v[2] = a[2]; r.v[3] = a[3];
        r.v[4] = b[0]; r.v[5] = b[1]; r.v[6] = b[2]; r.v[7] = b[3];
    } else {
        short8 s = *(const short8*)((const short*)p + idx);
        #pragma unroll
        for (int t = 0; t < 8; ++t) r.v[t] = bf2f(s[t]);
    }
    return r;
}

// Detect dtype of W_Q: if fp32, low half-words of floats are random bit
// patterns -> ~49% decode to |bf16|>8 (or NaN). If bf16, all |w| <= ~0.5.
__global__ void detect_dtype(const short* wq, int* flag) {
    int tid = threadIdx.x;   // 64 threads, 1 block
    int cnt = 0;
    for (int i = tid; i < 512; i += 64) {
        float v = bf2f(wq[i]);
        if (!(fabsf(v) < 8.0f)) cnt++;   // true for NaN as well
    }
    #pragma unroll
    for (int d = 1; d < 64; d <<= 1) cnt += __shfl_xor(cnt, d);
    if (tid == 0) flag[0] = (cnt > 16) ? 1 : 0;   // 1 = fp32, 0 = bf16
}

template<bool FP32>
__global__ __launch_bounds__(256, 2)
void na_fused(const void* __restrict__ hX, const void* __restrict__ hE,
              const int* __restrict__ mask, const void* __restrict__ WQ,
              const void* __restrict__ WK, const void* __restrict__ WV,
              const void* __restrict__ WO, void* __restrict__ out,
              const int* __restrict__ flag)
{
    // uniform early-out if the other variant is the active one
    if ((flag[0] != 0) != FP32) return;

    __shared__ alignas(16) short sA[128 * LSTR];   // e-tile -> HK -> HV (bf16)
    __shared__ alignas(16) float sXf[4 * 128];     // x rows (fp32)
    __shared__ alignas(16) int   sMask[128];       // 4 nodes x 32
    __shared__ alignas(16) float sQ[4 * 128];      // q rows (fp32)
    __shared__ alignas(16) float sS[512];          // scores -> attn [node][h][k]
    __shared__ alignas(16) float sAInv[16];        // 1/(attn_sum) per (node,h)
    __shared__ alignas(16) float sTmp[512];        // half-combine scratch
    __shared__ alignas(16) float sCat[4 * 384];    // [mean|sum|max] per node

    const int tid  = threadIdx.x;
    const int lane = tid & 63;
    const int w    = tid >> 6;      // wave 0..3 (owns output channels 32w..32w+31)
    const int quad = lane >> 4;
    const int l15  = lane & 15;
    const int nb   = blockIdx.x * NPB;   // first node of this block

    // ---------------- stage e tile (128x128), x rows, mask ----------------
    const size_t ebase = (size_t)nb * (KN * CDIM);
    for (int it = 0; it < 8; ++it) {
        int chunk = it * 256 + tid;            // 2048 chunks of 8 elems
        int row = chunk >> 4, cc = chunk & 15;
        short8 v = load8bf<FP32>(hE, ebase + (size_t)chunk * 8);
        *(short8*)(&sA[row * LSTR + cc * 8]) = v;
    }
    if (tid < 64) {
        f8 xv = loadf8<FP32>(hX, (size_t)nb * CDIM + tid * 8);
        #pragma unroll
        for (int t = 0; t < 8; ++t) sXf[tid * 8 + t] = xv.v[t];
    } else if (tid < 192) {
        int t = tid - 64;
        sMask[t] = mask[(size_t)nb * KN + t];
    }
    __syncthreads();

    // ---------------- q = x @ WQ^T (VALU; tiny) ----------------
    {
        int c = tid & 127, half = tid >> 7;
        float acc0 = 0.f, acc1 = 0.f, acc2 = 0.f, acc3 = 0.f;
        for (int j8 = 0; j8 < 64; j8 += 8) {
            f8 wv = loadf8<FP32>(WQ, (size_t)c * CDIM + half * 64 + j8);
            const float* x0 = &sXf[0 * 128 + half * 64 + j8];
            const float* x1 = &sXf[1 * 128 + half * 64 + j8];
            const float* x2 = &sXf[2 * 128 + half * 64 + j8];
            const float* x3 = &sXf[3 * 128 + half * 64 + j8];
            #pragma unroll
            for (int t = 0; t < 8; ++t) {
                float wf = wv.v[t];
                acc0 += wf * x0[t];
                acc1 += wf * x1[t];
                acc2 += wf * x2[t];
                acc3 += wf * x3[t];
            }
        }
        if (half == 1) { sTmp[c] = acc0; sTmp[128 + c] = acc1; sTmp[256 + c] = acc2; sTmp[384 + c] = acc3; }
        __syncthreads();
        if (half == 0) {
            sQ[c]       = acc0 + sTmp[c];
            sQ[128 + c] = acc1 + sTmp[128 + c];
            sQ[256 + c] = acc2 + sTmp[256 + c];
            sQ[384 + c] = acc3 + sTmp[384 + c];
        }
        __syncthreads();
    }

    // ---------------- B-fragments for W_K / W_V ----------------
    // B[i][c] = W[c][i]; lane holds B[kk*32+quad*8+j][tile*16+l15], j=0..7
    short8 bk[2][4], bv[2][4];
    #pragma unroll
    for (int t2 = 0; t2 < 2; ++t2) {
        int c = (w * 2 + t2) * 16 + l15;
        #pragma unroll
        for (int kk = 0; kk < 4; ++kk) {
            size_t off = (size_t)c * CDIM + kk * 32 + quad * 8;
            bk[t2][kk] = load8bf<FP32>(WK, off);
            bv[t2][kk] = load8bf<FP32>(WV, off);
        }
    }

    // ---------------- MFMA: HK and HV into registers ----------------
    f32x4 accK[8][2], accV[8][2];
    #pragma unroll
    for (int mt = 0; mt < 8; ++mt) {
        short8 a[4];
        #pragma unroll
        for (int kk = 0; kk < 4; ++kk)
            a[kk] = *(const short8*)(&sA[(mt * 16 + l15) * LSTR + kk * 32 + quad * 8]);
        f32x4 ck0 = {0.f, 0.f, 0.f, 0.f}, ck1 = {0.f, 0.f, 0.f, 0.f};
        f32x4 cv0 = {0.f, 0.f, 0.f, 0.f}, cv1 = {0.f, 0.f, 0.f, 0.f};
        #pragma unroll
        for (int kk = 0; kk < 4; ++kk) {
            ck0 = __builtin_amdgcn_mfma_f32_16x16x32_bf16(a[kk], bk[0][kk], ck0, 0, 0, 0);
            ck1 = __builtin_amdgcn_mfma_f32_16x16x32_bf16(a[kk], bk[1][kk], ck1, 0, 0, 0);
            cv0 = __builtin_amdgcn_mfma_f32_16x16x32_bf16(a[kk], bv[0][kk], cv0, 0, 0, 0);
            cv1 = __builtin_amdgcn_mfma_f32_16x16x32_bf16(a[kk], bv[1][kk], cv1, 0, 0, 0);
        }
        accK[mt][0] = ck0; accK[mt][1] = ck1;
        accV[mt][0] = cv0; accV[mt][1] = cv1;
    }
    __syncthreads();   // all e-tile reads complete

    // ---------------- write HK over the dead e-tile (bf16) ----------------
    // C/D layout: global row = mt*16 + quad*4 + r, global col = w*32 + t2*16 + l15
    #pragma unroll
    for (int mt = 0; mt < 8; ++mt) {
        #pragma unroll
        for (int r = 0; r < 4; ++r) {
            int row = mt * 16 + quad * 4 + r;
            sA[row * LSTR + w * 32 + l15]      = f2bf(accK[mt][0][r]);
            sA[row * LSTR + w * 32 + 16 + l15] = f2bf(accK[mt][1][r]);
        }
    }
    __syncthreads();

    // ---------------- scores: plain VALU dot per (node, head, k) ----------------
    {
        const float scale = 0.17677669529663687f;  // 1/sqrt(32)
        for (int it = 0; it < 2; ++it) {
            int idx = it * 256 + tid;                  // 0..511
            int node = idx >> 7, rem = idx & 127;
            int h = rem >> 5, k = rem & 31;
            const short* hp = &sA[(node * 32 + k) * LSTR + h * 32];
            const float* qp = &sQ[node * 128 + h * 32];
            float s = 0.f;
            #pragma unroll
            for (int d8 = 0; d8 < 32; d8 += 8) {
                short8 hk8 = *(const short8*)(hp + d8);
                #pragma unroll
                for (int t = 0; t < 8; ++t)
                    s += qp[d8 + t] * bf2f(hk8[t]);
            }
            sS[node * 128 + h * 32 + k] = s * scale;
        }
    }
    __syncthreads();

    // ---------------- write HV over HK; softmax on scores ----------------
    #pragma unroll
    for (int mt = 0; mt < 8; ++mt) {
        #pragma unroll
        for (int r = 0; r < 4; ++r) {
            int row = mt * 16 + quad * 4 + r;
            sA[row * LSTR + w * 32 + l15]      = f2bf(accV[mt][0][r]);
            sA[row * LSTR + w * 32 + 16 + l15] = f2bf(accV[mt][1][r]);
        }
    }
    if (tid < 16) {
        int node = tid >> 2;
        const int* mp = &sMask[node * 32];
        float* sp = &sS[node * 128 + (tid & 3) * 32];
        float m = -3.0e38f;
        for (int k = 0; k < KN; ++k)
            m = fmaxf(m, (mp[k] > 0) ? sp[k] : -3.0e38f);
        float denom = 0.f;
        for (int k = 0; k < KN; ++k) {
            float e = __expf(fminf(sp[k] - m, 0.f)) * ((mp[k] > 0) ? 1.f : 0.f);
            sp[k] = e;
            denom += e;
        }
        float inv = (denom > 0.f) ? (1.f / denom) : 0.f;
        for (int k = 0; k < KN; ++k)
            sp[k] = sp[k] * inv;
        float asum = ((denom > 0.f) ? 1.0f : 0.0f) + 1e-8f;  // sum(attn) + 1e-8
        sAInv[tid] = 1.0f / asum;
    }
    __syncthreads();

    // ---------------- weighted sum / mean / max per channel ----------------
    for (int it = 0; it < 2; ++it) {
        int idx = it * 256 + tid;
        int node = idx >> 7, c = idx & 127, h = c >> 5;
        const float* ap = &sS[node * 128 + h * 32];
        const short* vp = &sA[node * 32 * LSTR + c];
        float ws = 0.f, mx = -3.0e38f;
        #pragma unroll
        for (int k = 0; k < KN; ++k) {
            float pv = ap[k] * bf2f(vp[k * LSTR]);
            ws += pv;
            mx = fmaxf(mx, pv);
        }
        sCat[node * 384 + c]       = ws * sAInv[node * 4 + h];  // mean
        sCat[node * 384 + 128 + c] = ws;                        // sum
        sCat[node * 384 + 256 + c] = mx;                        // max
    }
    __syncthreads();

    // ---------------- out = cat @ WO^T ----------------
    {
        int c = tid & 127, half = tid >> 7;
        float acc[4] = {0.f, 0.f, 0.f, 0.f};
        for (int j8 = 0; j8 < 192; j8 += 8) {
            f8 wv = loadf8<FP32>(WO, (size_t)c * 384 + half * 192 + j8);
            #pragma unroll
            for (int t = 0; t < 8; ++t) {
                float wf = wv.v[t];
                #pragma unroll
                for (int n = 0; n < 4; ++n)
                    acc[n] += wf * sCat[n * 384 + half * 192 + j8 + t];
            }
        }
        if (half == 1) { sTmp[c] = acc[0]; sTmp[128 + c] = acc[1]; sTmp[256 + c] = acc[2]; sTmp[384 + c] = acc[3]; }
        __syncthreads();
        if (half == 0) {
            #pragma unroll
            for (int n = 0; n < 4; ++n) {
                float val = acc[n] + sTmp[n * 128 + c];
                if constexpr (FP32)
                    ((float*)out)[(size_t)(nb + n) * 128 + c] = val;
                else
                    ((short*)out)[(size_t)(nb + n) * 128 + c] = f2bf(val);
            }
        }
    }
}

extern "C" void kernel_launch(void* const* d_in, const int* in_sizes, int n_in,
                              void* d_out, int out_size, void* d_ws, size_t ws_size,
                              hipStream_t stream) {
    (void)in_sizes; (void)n_in; (void)ws_size; (void)out_size;
    const void* hX   = d_in[0];
    const void* hE   = d_in[1];
    const int*  mask = (const int*)d_in[2];
    const void* WQ   = d_in[3];
    const void* WK   = d_in[4];
    const void* WV   = d_in[5];
    const void* WO   = d_in[6];
    int* flag = (int*)d_ws;

    detect_dtype<<<1, 64, 0, stream>>>((const short*)WQ, flag);
    dim3 grid(4096), block(256);
    na_fused<false><<<grid, block, 0, stream>>>(hX, hE, mask, WQ, WK, WV, WO, d_out, flag);
    na_fused<true ><<<grid, block, 0, stream>>>(hX, hE, mask, WQ, WK, WV, WO, d_out, flag);
}